// Round 7
// baseline (1386.161 us; speedup 1.0000x reference)
//
#include <hip/hip_runtime.h>
#include <hip/hip_bf16.h>

// LSTM: B=256, T=512, I=256, H=128 (4H=512 gates), then MLP 128->64->32->4.
// ROUND 15: phase-interleaved 2-group LSTM (the work-neutral pipeline).
//   Each block owns 8 batches = two 4-batch groups A,B. Phase = {one group's
//   16 MFMA/wave (+in-phase sel4)} || {other group's gate math, 1 unit/lane}.
//   2 phases advance both groups 1 step. Matrix work per batch UNCHANGED
//   (round-3's sin), units/lane/phase = 1 (round-13's sin). MFMA result
//   crosses the barrier as 4 floats (sel4 in-phase) -> VGPR fits 128.
//   32 lstm blocks; single h buffer per group (all hazards barrier-separated).
//   GEMM/conv/head/schedule unchanged from round 14.
//
//   gx gate-plane layout (unchanged):
//     idx(g,t,blk2,wj,L) = (((g*TC+t)*64 + blk2)*512) + wj*64 + L
//     group A: blk2=2*blk, group B: blk2=2*blk+1 (b0 = 8*blk).

#define TC       64
#define NCHUNK   8
#define BATCH    256
#define TSEQ     512
#define ISZ      256
#define HSZ      128
#define NLB      32               // lstm blocks (8 batches each)
#define NGB      (2 * TC * 4)     // 512 gemm blocks
#define HROW     144              // shorts; 72 dwords = 8 mod 32 -> 2-way only
#define GX_PER_T 131072
#define GXCH     ((size_t)TC * GX_PER_T)
#define STRT     32768            // per-plane step stride in shorts (64*512)

#define XN       (BATCH * TSEQ * ISZ)
#define WIHN     (4 * HSZ * ISZ)
#define WHHN     (4 * HSZ * HSZ)
#define CVT_UNITS ((XN + WIHN + WHHN) / 8)

typedef __attribute__((ext_vector_type(8))) short short8;
typedef __attribute__((ext_vector_type(4))) float f32x4;

__device__ __forceinline__ void barrier_nodrain() {
    __asm__ __volatile__("s_waitcnt lgkmcnt(0)\n\ts_barrier" ::: "memory");
}
__device__ __forceinline__ float fast_rcp(float x) {
    return __builtin_amdgcn_rcpf(x);
}
__device__ __forceinline__ float sigmoidf_(float x) {
    return fast_rcp(1.0f + __expf(-x));
}
__device__ __forceinline__ float tanhf_(float x) {
    float e = __expf(2.0f * x);
    return 1.0f - 2.0f * fast_rcp(e + 1.0f);
}
__device__ __forceinline__ unsigned short f2bf(float x) {
    union { float f; unsigned u; } v; v.f = x;
    unsigned r = v.u + 0x7fffu + ((v.u >> 16) & 1u);
    return (unsigned short)(r >> 16);
}
__device__ __forceinline__ float bf2f(unsigned short b) {
    union { unsigned u; float f; } v;
    v.u = ((unsigned)b) << 16;
    return v.f;
}
__device__ __forceinline__ unsigned packbf(float lo, float hi) {
    __hip_bfloat162 h2 = __float22bfloat162_rn(make_float2(lo, hi));
    union { __hip_bfloat162 h; unsigned u; } v; v.h = h2;
    return v.u;
}
__device__ __forceinline__ float sel4(f32x4 v, int r) {
    float s01 = (r & 1) ? v[1] : v[0];
    float s23 = (r & 1) ? v[3] : v[2];
    return (r & 2) ? s23 : s01;
}

// ---------------------------------------------------------------------------
__global__ __launch_bounds__(256) void conv_kernel(
    const float* __restrict__ x, const float* __restrict__ Wih,
    const float* __restrict__ Whh,
    unsigned short* __restrict__ xb, unsigned short* __restrict__ wihb,
    unsigned short* __restrict__ whhb)
{
    const size_t stride = (size_t)gridDim.x * 256;
    for (size_t u = (size_t)blockIdx.x * 256 + threadIdx.x; u < (size_t)CVT_UNITS;
         u += stride) {
        const size_t e0 = u * 8;
        const float* s; unsigned short* d;
        if (e0 < (size_t)XN)               { s = x + e0;                 d = xb + e0; }
        else if (e0 < (size_t)(XN + WIHN)) { s = Wih + (e0 - XN);        d = wihb + (e0 - XN); }
        else                               { s = Whh + (e0 - XN - WIHN); d = whhb + (e0 - XN - WIHN); }
        float4 f0 = *(const float4*)(s);
        float4 f1 = *(const float4*)(s + 4);
        *(uint4*)(d) = (uint4){packbf(f0.x, f0.y), packbf(f0.z, f0.w),
                               packbf(f1.x, f1.y), packbf(f1.z, f1.w)};
    }
}

// ---------------------------------------------------------------------------
__global__ __launch_bounds__(512, 4) void fused_kernel(
    const unsigned short* __restrict__ xb, const unsigned short* __restrict__ wihb,
    const unsigned short* __restrict__ whhb,
    const float* __restrict__ bih, const float* __restrict__ bhh,
    const unsigned short* __restrict__ gxl, unsigned short* __restrict__ gxg,
    float* __restrict__ hc, int t0, int first, int run_lstm, int run_gemm)
{
    __shared__ __align__(16) char smem[32768];
    const int tid  = threadIdx.x;
    const int w    = tid >> 6;
    const int lane = tid & 63;
    const int n    = lane & 15;
    const int quad = lane >> 4;

    if (blockIdx.x >= NLB) {
        // ===================== GEMM role (gx for chunk at t0) ===============
        if (!run_gemm) return;
        short* As = (short*)smem;
        short* Bs = (short*)(smem + 16384);

        const int gb = (int)blockIdx.x - NLB;
        const int nt = gb & 3;
        const int mt = gb >> 2;
        const int tl = mt >> 1;
        const int b0 = (mt & 1) * 128;
        const int n0 = nt * 128;

        const int mq = w & 1;
        const int nq = w >> 1;

        const int srow = tid >> 2;
        const int skh  = (tid & 3) * 8;

        const unsigned short* xr = xb + ((size_t)(b0 + srow) * TSEQ + (size_t)(t0 + tl)) * ISZ + skh;
        const unsigned short* wr = wihb + (size_t)(n0 + srow) * ISZ + skh;

        f32x4 acc[4][2];
#pragma unroll
        for (int mi = 0; mi < 4; ++mi)
#pragma unroll
            for (int ni = 0; ni < 2; ++ni)
                acc[mi][ni] = (f32x4){0.f, 0.f, 0.f, 0.f};

        *(short8*)(&As[srow * 32 + skh]) = *(const short8*)(xr);
        *(short8*)(&Bs[srow * 32 + skh]) = *(const short8*)(wr);
        barrier_nodrain();

        for (int ks = 0; ks < 8; ++ks) {
            const int cur = (ks & 1) * 4096;
            const int nxt = 4096 - cur;
            short8 va, vb;
            if (ks < 7) {
                va = *(const short8*)(xr + (ks + 1) * 32);
                vb = *(const short8*)(wr + (ks + 1) * 32);
            }
            short8 af[4], bfr[2];
#pragma unroll
            for (int mi = 0; mi < 4; ++mi)
                af[mi] = *(const short8*)(&As[cur + (mq * 64 + mi * 16 + n) * 32 + quad * 8]);
#pragma unroll
            for (int ni = 0; ni < 2; ++ni)
                bfr[ni] = *(const short8*)(&Bs[cur + (nq * 32 + ni * 16 + n) * 32 + quad * 8]);
#pragma unroll
            for (int mi = 0; mi < 4; ++mi)
#pragma unroll
                for (int ni = 0; ni < 2; ++ni)
                    acc[mi][ni] = __builtin_amdgcn_mfma_f32_16x16x32_bf16(
                        af[mi], bfr[ni], acc[mi][ni], 0, 0, 0);
            if (ks < 7) {
                *(short8*)(&As[nxt + srow * 32 + skh]) = va;
                *(short8*)(&Bs[nxt + srow * 32 + skh]) = vb;
            }
            barrier_nodrain();
        }

#pragma unroll
        for (int ni = 0; ni < 2; ++ni) {
            const int j    = nq * 32 + ni * 16 + n;
            const int gate = n0 + j;
            const float bias = bih[gate] + bhh[gate];
            const int wj = nq * 2 + ni;
#pragma unroll
            for (int mi = 0; mi < 4; ++mi) {
                const int bb   = b0 + mq * 64 + mi * 16 + quad * 4;
                const int blk2 = bb >> 2;
                const size_t idx = ((((size_t)nt * TC + tl) * 64 + blk2) * 512) +
                                   (size_t)wj * 64 + (size_t)n * 4;
                const unsigned lo = packbf(acc[mi][ni][0] + bias, acc[mi][ni][1] + bias);
                const unsigned hi = packbf(acc[mi][ni][2] + bias, acc[mi][ni][3] + bias);
                *(uint2*)(&gxg[idx]) = (uint2){lo, hi};
            }
        }
        return;
    }

    // ============= LSTM role: 2 groups x 4 batches, phase-interleaved =======
    if (!run_lstm) return;
    __builtin_amdgcn_s_setprio(1);
    short* hA = (short*)smem;                       // [4][HROW] group A h
    short* hB = (short*)(smem + 4 * HROW * 2);      // [4][HROW] group B h

    const int blk  = (int)blockIdx.x;    // 0..31
    const int b0   = blk * 8;            // A: b0..b0+3, B: b0+4..b0+7
    const int nb   = lane & 3;
    const int jl   = lane >> 2;
    const int j    = 16 * w + jl;
    const int rsel = jl & 3;

    // static A-frags (shared by both groups)
    short8 Af[4][4];
#pragma unroll
    for (int g = 0; g < 4; ++g) {
        const unsigned short* rowb = whhb + (size_t)(128 * g + 16 * w + n) * HSZ + 8 * quad;
#pragma unroll
        for (int ks = 0; ks < 4; ++ks)
            Af[g][ks] = *(const short8*)(rowb + 32 * ks);
    }

    float cA = 0.f, cB = 0.f, hlA = 0.f, hlB = 0.f;
    {
        unsigned short h0a = 0, h0b = 0;
        if (!first) {
            cA  = hc[(size_t)BATCH * HSZ + (size_t)(b0 + nb) * HSZ + j];
            cB  = hc[(size_t)BATCH * HSZ + (size_t)(b0 + 4 + nb) * HSZ + j];
            h0a = f2bf(hc[(size_t)(b0 + nb) * HSZ + j]);
            h0b = f2bf(hc[(size_t)(b0 + 4 + nb) * HSZ + j]);
        }
        *(unsigned short*)&hA[nb * HROW + j] = h0a;
        *(unsigned short*)&hB[nb * HROW + j] = h0b;
    }

    // gx pointers: group A blk2=2*blk, group B blk2=2*blk+1
    const unsigned short* gpA[4];
    const unsigned short* gpB[4];
#pragma unroll
    for (int g = 0; g < 4; ++g) {
        gpA[g] = gxl + ((size_t)g * TC * 64 + 2 * blk) * 512 + w * 64 + lane;
        gpB[g] = gpA[g] + 512;
    }
    unsigned short gqA[2][4], gqB[2][4];     // PF=2 ring per group
#pragma unroll
    for (int s = 0; s < 2; ++s)
#pragma unroll
        for (int g = 0; g < 4; ++g) {
            gqA[s][g] = gpA[g][(size_t)s * STRT];
            gqB[s][g] = gpB[g][(size_t)s * STRT];
        }

    float sA0 = 0.f, sA1 = 0.f, sA2 = 0.f, sA3 = 0.f;
    float sB0, sB1, sB2, sB3;

    barrier_nodrain();   // init h visible to all waves

    // P0: MFMA_B on h_B(init) -> sB (no LDS writes, no barrier needed)
    {
        short8 Bf_[4];
#pragma unroll
        for (int ks = 0; ks < 4; ++ks)
            Bf_[ks] = *(const short8*)(&hB[nb * HROW + 32 * ks + 8 * quad]);
        f32x4 acc_[4];
#pragma unroll
        for (int g = 0; g < 4; ++g)
            acc_[g] = __builtin_amdgcn_mfma_f32_16x16x32_bf16(
                Af[g][0], Bf_[0], (f32x4){0.f, 0.f, 0.f, 0.f}, 0, 0, 0);
#pragma unroll
        for (int ks = 1; ks < 4; ++ks)
#pragma unroll
            for (int g = 0; g < 4; ++g)
                acc_[g] = __builtin_amdgcn_mfma_f32_16x16x32_bf16(
                    Af[g][ks], Bf_[ks], acc_[g], 0, 0, 0);
        sB0 = sel4(acc_[0], rsel); sB1 = sel4(acc_[1], rsel);
        sB2 = sel4(acc_[2], rsel); sB3 = sel4(acc_[3], rsel);
    }

    // PHASE: {ds_read Bf of HSRC; gates of other group (SG,GQ)->HDST;
    //         16-MFMA chain; in-phase sel4 -> SA; reload GQ slot; barrier}
#define PHASE(HSRC, SA0_, SA1_, SA2_, SA3_, SG0_, SG1_, SG2_, SG3_,            \
              GQ, GP, TF, cG, hlG, HDST)                                       \
    {                                                                          \
        short8 Bf_[4];                                                         \
        _Pragma("unroll")                                                      \
        for (int ks_ = 0; ks_ < 4; ++ks_)                                      \
            Bf_[ks_] = *(const short8*)(&HSRC[nb * HROW + 32 * ks_ + 8 * quad]);\
        {                                                                      \
            const float x0_ = SG0_ + bf2f(GQ[0]);                              \
            const float x1_ = SG1_ + bf2f(GQ[1]);                              \
            const float x2_ = SG2_ + bf2f(GQ[2]);                              \
            const float x3_ = SG3_ + bf2f(GQ[3]);                              \
            const float ig_ = sigmoidf_(x0_);                                  \
            const float fg_ = sigmoidf_(x1_);                                  \
            const float gg_ = tanhf_(x2_);                                     \
            const float og_ = sigmoidf_(x3_);                                  \
            cG = fg_ * cG + ig_ * gg_;                                         \
            hlG = og_ * tanhf_(cG);                                            \
            *(unsigned short*)&HDST[nb * HROW + j] = f2bf(hlG);                \
        }                                                                      \
        f32x4 acc_[4];                                                         \
        _Pragma("unroll")                                                      \
        for (int g_ = 0; g_ < 4; ++g_)                                         \
            acc_[g_] = __builtin_amdgcn_mfma_f32_16x16x32_bf16(                \
                Af[g_][0], Bf_[0], (f32x4){0.f, 0.f, 0.f, 0.f}, 0, 0, 0);      \
        _Pragma("unroll")                                                      \
        for (int ks_ = 1; ks_ < 4; ++ks_)                                      \
            _Pragma("unroll")                                                  \
            for (int g_ = 0; g_ < 4; ++g_)                                     \
                acc_[g_] = __builtin_amdgcn_mfma_f32_16x16x32_bf16(            \
                    Af[g_][ks_], Bf_[ks_], acc_[g_], 0, 0, 0);                 \
        SA0_ = sel4(acc_[0], rsel); SA1_ = sel4(acc_[1], rsel);                \
        SA2_ = sel4(acc_[2], rsel); SA3_ = sel4(acc_[3], rsel);                \
        {                                                                      \
            const int tc_ = (TF) < TC ? (TF) : (TC - 1);                       \
            _Pragma("unroll")                                                  \
            for (int g_ = 0; g_ < 4; ++g_)                                     \
                GQ[g_] = GP[g_][(size_t)tc_ * STRT];                           \
        }                                                                      \
        barrier_nodrain();                                                     \
    }

    for (int t = 0; t < TC; t += 2) {
        // P1(t): MFMA_A(h_A(t-1)) -> sA ; gates_B: h_B(t) from sB
        PHASE(hA, sA0, sA1, sA2, sA3, sB0, sB1, sB2, sB3,
              gqB[0], gpB, t + 2, cB, hlB, hB);
        // P2(t): MFMA_B(h_B(t)) -> sB ; gates_A: h_A(t) from sA
        PHASE(hB, sB0, sB1, sB2, sB3, sA0, sA1, sA2, sA3,
              gqA[0], gpA, t + 2, cA, hlA, hA);
        // P1(t+1)
        PHASE(hA, sA0, sA1, sA2, sA3, sB0, sB1, sB2, sB3,
              gqB[1], gpB, t + 3, cB, hlB, hB);
        // P2(t+1)
        PHASE(hB, sB0, sB1, sB2, sB3, sA0, sA1, sA2, sA3,
              gqA[1], gpA, t + 3, cA, hlA, hA);
    }
#undef PHASE

    hc[(size_t)(b0 + nb) * HSZ + j] = hlA;
    hc[(size_t)BATCH * HSZ + (size_t)(b0 + nb) * HSZ + j] = cA;
    hc[(size_t)(b0 + 4 + nb) * HSZ + j] = hlB;
    hc[(size_t)BATCH * HSZ + (size_t)(b0 + 4 + nb) * HSZ + j] = cB;
}

// ---------------------------------------------------------------------------
__global__ __launch_bounds__(64) void head_kernel(
    const float* __restrict__ hc,
    const float* __restrict__ W1, const float* __restrict__ b1,
    const float* __restrict__ W2, const float* __restrict__ b2,
    const float* __restrict__ W3, const float* __restrict__ b3,
    float* __restrict__ out)
{
    __shared__ float hs[HSZ];
    __shared__ float o1[64];
    __shared__ float o2[32];
    const int bidx = blockIdx.x;
    const int t = threadIdx.x;
    hs[t]      = hc[bidx * HSZ + t];
    hs[t + 64] = hc[bidx * HSZ + t + 64];
    __syncthreads();
    {
        float a = b1[t];
#pragma unroll 8
        for (int k = 0; k < HSZ; ++k) a += W1[t * HSZ + k] * hs[k];
        o1[t] = fmaxf(a, 0.0f);
    }
    __syncthreads();
    if (t < 32) {
        float a = b2[t];
#pragma unroll 8
        for (int k = 0; k < 64; ++k) a += W2[t * 64 + k] * o1[k];
        o2[t] = fmaxf(a, 0.0f);
    }
    __syncthreads();
    if (t < 4) {
        float a = b3[t];
#pragma unroll
        for (int k = 0; k < 32; ++k) a += W3[t * 32 + k] * o2[k];
        out[bidx * 4 + t] = a;
    }
}

// ---------------------------------------------------------------------------
extern "C" void kernel_launch(void* const* d_in, const int* in_sizes, int n_in,
                              void* d_out, int out_size, void* d_ws, size_t ws_size,
                              hipStream_t stream) {
    const float* x   = (const float*)d_in[0];
    const float* Wih = (const float*)d_in[1];
    const float* Whh = (const float*)d_in[2];
    const float* bih = (const float*)d_in[3];
    const float* bhh = (const float*)d_in[4];
    const float* W1  = (const float*)d_in[5];
    const float* b1  = (const float*)d_in[6];
    const float* W2  = (const float*)d_in[7];
    const float* b2  = (const float*)d_in[8];
    const float* W3  = (const float*)d_in[9];
    const float* b3  = (const float*)d_in[10];
    float* out = (float*)d_out;

    const size_t GXB = GXCH * sizeof(unsigned short);
    unsigned short* gx0 = (unsigned short*)d_ws;
    unsigned short* gx1 = (unsigned short*)((char*)d_ws + GXB);
    float* hc = (float*)((char*)d_ws + 2 * GXB);
    unsigned short* xb   = (unsigned short*)((char*)d_ws + 2 * GXB + 262144);
    unsigned short* wihb = xb + (size_t)XN;
    unsigned short* whhb = wihb + WIHN;

    conv_kernel<<<dim3(2048), 256, 0, stream>>>(x, Wih, Whh, xb, wihb, whhb);

    for (int k = 0; k <= NCHUNK; ++k) {
        const int run_gemm = (k < NCHUNK);
        const int run_lstm = (k > 0);
        unsigned short* gg = (k & 1) ? gx1 : gx0;
        const unsigned short* gl = ((k - 1) & 1) ? gx1 : gx0;
        fused_kernel<<<dim3(NLB + NGB), 512, 0, stream>>>(
            xb, wihb, whhb, bih, bhh, gl, gg, hc,
            k * TC, (k == 1) ? 1 : 0, run_lstm, run_gemm);
    }

    head_kernel<<<dim3(BATCH), 64, 0, stream>>>(hc, W1, b1, W2, b2, W3, b3, out);
}

// Round 8
// 532.746 us; speedup vs baseline: 2.6019x; 2.6019x over previous
//
#include <hip/hip_runtime.h>
#include <hip/hip_bf16.h>

// LSTM: B=256, T=512, I=256, H=128 (4H=512 gates), then MLP 128->64->32->4.
// ROUND 16: ONE lever vs round 14 — TC 64->128, NCHUNK 8->4. Fewer dispatch
//   boundaries: each fused launch re-pays Af init + hc round-trip + gq ring
//   priming + ramp (~5-7us); halving launches should recover round-0's
//   standalone 790ns/step rate (vs ~906ns in 64-step chunks).
//   LSTM role: round-2 structure EXACTLY (1 unit/lane, rsel in-lane extract,
//   single 4-deep MFMA chains, PF=4 gx ring, 1 barrier/step). All phase/
//   group/RB restructures are measured-bad (r11/r12/r13/r15) — never again.
//   Schedule: conv; skewed fused k=0..4 (GEMM chunk k + LSTM chunk k-1); head.
//
//   gx gate-plane layout (unchanged):
//     idx(g,t,blk2,wj,L) = (((g*TC+t)*64 + blk2)*512) + wj*64 + L
//     blk2=batch>>2, j=gate&127, wj=j>>4, L=(j&15)*4+(batch&3).

#define TC       128
#define NCHUNK   4
#define BATCH    256
#define TSEQ     512
#define ISZ      256
#define HSZ      128
#define RB       4
#define NBLK     (BATCH / RB)     // 64 lstm blocks
#define NGB      (2 * TC * 4)     // 1024 gemm blocks
#define HROW     144              // shorts; 72 dwords = 8 mod 32 -> 2-way only
#define GX_PER_T 131072           // gx elements per timestep (all 4 planes)
#define GXCH     ((size_t)TC * GX_PER_T)   // shorts per gx buffer (33.55MB)
#define STRT     32768            // per-t stride in shorts (64*512)
#define PF       4                // gx prefetch depth in steps

#define XN       (BATCH * TSEQ * ISZ)   // 33554432 x elems
#define WIHN     (4 * HSZ * ISZ)        // 131072
#define WHHN     (4 * HSZ * HSZ)        // 65536
#define CVT_UNITS ((XN + WIHN + WHHN) / 8)

typedef __attribute__((ext_vector_type(8))) short short8;
typedef __attribute__((ext_vector_type(4))) float f32x4;

__device__ __forceinline__ void barrier_nodrain() {
    // s_barrier WITHOUT the compiler's vmcnt(0) drain: LDS consistency only.
    __asm__ __volatile__("s_waitcnt lgkmcnt(0)\n\ts_barrier" ::: "memory");
}

__device__ __forceinline__ float fast_rcp(float x) {
    return __builtin_amdgcn_rcpf(x);
}
__device__ __forceinline__ float sigmoidf_(float x) {
    return fast_rcp(1.0f + __expf(-x));
}
__device__ __forceinline__ float tanhf_(float x) {
    float e = __expf(2.0f * x);               // inf-safe
    return 1.0f - 2.0f * fast_rcp(e + 1.0f);
}
__device__ __forceinline__ unsigned short f2bf(float x) {  // fp32 -> bf16 RNE
    union { float f; unsigned u; } v; v.f = x;
    unsigned r = v.u + 0x7fffu + ((v.u >> 16) & 1u);
    return (unsigned short)(r >> 16);
}
__device__ __forceinline__ float bf2f(unsigned short b) {
    union { unsigned u; float f; } v;
    v.u = ((unsigned)b) << 16;
    return v.f;
}
__device__ __forceinline__ unsigned packbf(float lo, float hi) {  // packed HW cvt
    __hip_bfloat162 h2 = __float22bfloat162_rn(make_float2(lo, hi));
    union { __hip_bfloat162 h; unsigned u; } v; v.h = h2;
    return v.u;
}
__device__ __forceinline__ float sel4(f32x4 v, int r) {   // v[r], 3 cndmask
    float s01 = (r & 1) ? v[1] : v[0];
    float s23 = (r & 1) ? v[3] : v[2];
    return (r & 2) ? s23 : s01;
}

// ---------------------------------------------------------------------------
// Convert x / Wih / Whh to bf16 workspace copies. Pure BW (~201 MB).
__global__ __launch_bounds__(256) void conv_kernel(
    const float* __restrict__ x, const float* __restrict__ Wih,
    const float* __restrict__ Whh,
    unsigned short* __restrict__ xb, unsigned short* __restrict__ wihb,
    unsigned short* __restrict__ whhb)
{
    const size_t stride = (size_t)gridDim.x * 256;
    for (size_t u = (size_t)blockIdx.x * 256 + threadIdx.x; u < (size_t)CVT_UNITS;
         u += stride) {
        const size_t e0 = u * 8;
        const float* s; unsigned short* d;
        if (e0 < (size_t)XN)               { s = x + e0;                 d = xb + e0; }
        else if (e0 < (size_t)(XN + WIHN)) { s = Wih + (e0 - XN);        d = wihb + (e0 - XN); }
        else                               { s = Whh + (e0 - XN - WIHN); d = whhb + (e0 - XN - WIHN); }
        float4 f0 = *(const float4*)(s);
        float4 f1 = *(const float4*)(s + 4);
        *(uint4*)(d) = (uint4){packbf(f0.x, f0.y), packbf(f0.z, f0.w),
                               packbf(f1.x, f1.y), packbf(f1.z, f1.w)};
    }
}

// ---------------------------------------------------------------------------
// Fused kernel: blocks [0,NBLK) lstm (reads gxl), [NBLK,..) gemm (writes gxg
// for timestep base t0). Either role can be disabled.
__global__ __launch_bounds__(512, 2) void fused_kernel(
    const unsigned short* __restrict__ xb, const unsigned short* __restrict__ wihb,
    const unsigned short* __restrict__ whhb,
    const float* __restrict__ bih, const float* __restrict__ bhh,
    const unsigned short* __restrict__ gxl, unsigned short* __restrict__ gxg,
    float* __restrict__ hc, int t0, int first, int run_lstm, int run_gemm)
{
    __shared__ __align__(16) char smem[32768];
    const int tid  = threadIdx.x;
    const int w    = tid >> 6;
    const int lane = tid & 63;
    const int n    = lane & 15;
    const int quad = lane >> 4;

    if (blockIdx.x >= NBLK) {
        // ===================== GEMM role (gx for chunk at t0) ===============
        if (!run_gemm) return;
        short* As = (short*)smem;            // [2][128*32] bf16, 16 KB
        short* Bs = (short*)(smem + 16384);  // [2][128*32] bf16, 16 KB

        const int gb = (int)blockIdx.x - NBLK;
        const int nt = gb & 3;               // gate plane
        const int mt = gb >> 2;
        const int tl = mt >> 1;              // timestep within chunk (0..127)
        const int b0 = (mt & 1) * 128;       // batch half
        const int n0 = nt * 128;

        const int mq = w & 1;                // wave grid 2(m) x 4(n)
        const int nq = w >> 1;

        const int srow = tid >> 2;           // 0..127 staging row
        const int skh  = (tid & 3) * 8;      // elem offset within 32-k slice

        const unsigned short* xr = xb + ((size_t)(b0 + srow) * TSEQ + (size_t)(t0 + tl)) * ISZ + skh;
        const unsigned short* wr = wihb + (size_t)(n0 + srow) * ISZ + skh;

        f32x4 acc[4][2];
#pragma unroll
        for (int mi = 0; mi < 4; ++mi)
#pragma unroll
            for (int ni = 0; ni < 2; ++ni)
                acc[mi][ni] = (f32x4){0.f, 0.f, 0.f, 0.f};

        *(short8*)(&As[srow * 32 + skh]) = *(const short8*)(xr);
        *(short8*)(&Bs[srow * 32 + skh]) = *(const short8*)(wr);
        barrier_nodrain();

        for (int ks = 0; ks < 8; ++ks) {
            const int cur = (ks & 1) * 4096;
            const int nxt = 4096 - cur;
            short8 va, vb;
            if (ks < 7) {
                va = *(const short8*)(xr + (ks + 1) * 32);
                vb = *(const short8*)(wr + (ks + 1) * 32);
            }
            short8 af[4], bfr[2];
#pragma unroll
            for (int mi = 0; mi < 4; ++mi)
                af[mi] = *(const short8*)(&As[cur + (mq * 64 + mi * 16 + n) * 32 + quad * 8]);
#pragma unroll
            for (int ni = 0; ni < 2; ++ni)
                bfr[ni] = *(const short8*)(&Bs[cur + (nq * 32 + ni * 16 + n) * 32 + quad * 8]);
#pragma unroll
            for (int mi = 0; mi < 4; ++mi)
#pragma unroll
                for (int ni = 0; ni < 2; ++ni)
                    acc[mi][ni] = __builtin_amdgcn_mfma_f32_16x16x32_bf16(
                        af[mi], bfr[ni], acc[mi][ni], 0, 0, 0);
            if (ks < 7) {
                *(short8*)(&As[nxt + srow * 32 + skh]) = va;
                *(short8*)(&Bs[nxt + srow * 32 + skh]) = vb;
            }
            barrier_nodrain();
        }

        // epilogue: bias + bf16, gate-plane layout, 8-B contiguous stores.
#pragma unroll
        for (int ni = 0; ni < 2; ++ni) {
            const int j    = nq * 32 + ni * 16 + n;
            const int gate = n0 + j;
            const float bias = bih[gate] + bhh[gate];
            const int wj = nq * 2 + ni;                       // j >> 4
#pragma unroll
            for (int mi = 0; mi < 4; ++mi) {
                const int bb   = b0 + mq * 64 + mi * 16 + quad * 4;
                const int blk2 = bb >> 2;
                const size_t idx = ((((size_t)nt * TC + tl) * 64 + blk2) * 512) +
                                   (size_t)wj * 64 + (size_t)n * 4;
                const unsigned lo = packbf(acc[mi][ni][0] + bias, acc[mi][ni][1] + bias);
                const unsigned hi = packbf(acc[mi][ni][2] + bias, acc[mi][ni][3] + bias);
                *(uint2*)(&gxg[idx]) = (uint2){lo, hi};
            }
        }
        return;
    }

    // ======================= LSTM role (round-2 structure) ==================
    if (!run_lstm) return;
    __builtin_amdgcn_s_setprio(1);   // latency-critical chain wins issue arb
    short* h_lds = (short*)smem;     // [2*RB*HROW] bf16 double-buffered h

    const int blk  = (int)blockIdx.x;
    const int b0   = blk * RB;
    const int nb   = lane & 3;           // unit batch
    const int jl   = lane >> 2;          // unit j-local 0..15
    const int j    = 16 * w + jl;        // unit hidden index
    const int rsel = jl & 3;             // D-reg holding this unit's gate

    // static A-frags straight from pre-converted bf16 Whh
    short8 Af[4][4];
#pragma unroll
    for (int g = 0; g < 4; ++g) {
        const unsigned short* rowb = whhb + (size_t)(128 * g + 16 * w + n) * HSZ + 8 * quad;
#pragma unroll
        for (int ks = 0; ks < 4; ++ks)
            Af[g][ks] = *(const short8*)(rowb + 32 * ks);
    }

    // init unit state: every thread owns one (j, b) unit
    float c1 = 0.f, hl1 = 0.f;
    {
        unsigned short h0 = 0;
        if (!first) {
            c1 = hc[(size_t)BATCH * HSZ + (size_t)(b0 + nb) * HSZ + j];
            h0 = f2bf(hc[(size_t)(b0 + nb) * HSZ + j]);
        }
        *(unsigned short*)&h_lds[nb * HROW + j] = h0;   // buffer 0
    }

    // gx: 4 coalesced ushort loads per lane per step (one per gate plane)
    const unsigned short* gp[4];
#pragma unroll
    for (int g = 0; g < 4; ++g)
        gp[g] = gxl + (((size_t)g * TC) * 64 + blk) * 512 + (size_t)w * 64 + lane;

    unsigned short gq[PF][4];
#pragma unroll
    for (int d = 0; d < PF; ++d)
#pragma unroll
        for (int g = 0; g < 4; ++g)
            gq[d][g] = gp[g][(size_t)d * STRT];

    barrier_nodrain();

    for (int t = 0; t < TC; t += PF) {
#pragma unroll
        for (int u = 0; u < PF; ++u) {
            const int tt = t + u;
            const short* hb_r = h_lds + (u & 1) * (RB * HROW);
            short*       hb_w = h_lds + ((u & 1) ^ 1) * (RB * HROW);

            short8 Bf[4];
#pragma unroll
            for (int ks = 0; ks < 4; ++ks)
                Bf[ks] = *(const short8*)(&hb_r[nb * HROW + 32 * ks + 8 * quad]);

            // MFMAs: zero-C first, 4 independent 4-deep chains (one per gate)
            f32x4 acc[4];
#pragma unroll
            for (int g = 0; g < 4; ++g)
                acc[g] = __builtin_amdgcn_mfma_f32_16x16x32_bf16(
                    Af[g][0], Bf[0], (f32x4){0.f, 0.f, 0.f, 0.f}, 0, 0, 0);
#pragma unroll
            for (int ks = 1; ks < 4; ++ks)
#pragma unroll
                for (int g = 0; g < 4; ++g)
                    acc[g] = __builtin_amdgcn_mfma_f32_16x16x32_bf16(
                        Af[g][ks], Bf[ks], acc[g], 0, 0, 0);

            // in-lane gate extract: unit (jl,nb)'s value is THIS lane's
            // acc[g][rsel] (D row = 4*quad+reg = jl, D col batch = nb).
            const float s0 = sel4(acc[0], rsel) + bf2f(gq[u][0]);
            const float s1 = sel4(acc[1], rsel) + bf2f(gq[u][1]);
            const float s2 = sel4(acc[2], rsel) + bf2f(gq[u][2]);
            const float s3 = sel4(acc[3], rsel) + bf2f(gq[u][3]);

            // reload ring slot u (just consumed) for step tt+PF; vmcnt wait
            // for these loads lands PF steps from now.
            const int tf = (tt + PF < TC) ? (tt + PF) : (TC - 1);
#pragma unroll
            for (int g = 0; g < 4; ++g)
                gq[u][g] = gp[g][(size_t)tf * STRT];

            const float ig = sigmoidf_(s0);
            const float fg = sigmoidf_(s1);
            const float gg = tanhf_(s2);
            const float og = sigmoidf_(s3);
            c1  = fg * c1 + ig * gg;
            hl1 = og * tanhf_(c1);

            *(unsigned short*)&hb_w[nb * HROW + j] = f2bf(hl1);
            barrier_nodrain();
        }
    }

    hc[(size_t)(b0 + nb) * HSZ + j] = hl1;
    hc[(size_t)BATCH * HSZ + (size_t)(b0 + nb) * HSZ + j] = c1;
}

// ---------------------------------------------------------------------------
// MLP head: one block (64 threads) per batch row.
__global__ __launch_bounds__(64) void head_kernel(
    const float* __restrict__ hc,
    const float* __restrict__ W1, const float* __restrict__ b1,
    const float* __restrict__ W2, const float* __restrict__ b2,
    const float* __restrict__ W3, const float* __restrict__ b3,
    float* __restrict__ out)
{
    __shared__ float hs[HSZ];
    __shared__ float o1[64];
    __shared__ float o2[32];
    const int bidx = blockIdx.x;
    const int t = threadIdx.x;
    hs[t]      = hc[bidx * HSZ + t];
    hs[t + 64] = hc[bidx * HSZ + t + 64];
    __syncthreads();
    {
        float a = b1[t];
#pragma unroll 8
        for (int k = 0; k < HSZ; ++k) a += W1[t * HSZ + k] * hs[k];
        o1[t] = fmaxf(a, 0.0f);
    }
    __syncthreads();
    if (t < 32) {
        float a = b2[t];
#pragma unroll 8
        for (int k = 0; k < 64; ++k) a += W2[t * 64 + k] * o1[k];
        o2[t] = fmaxf(a, 0.0f);
    }
    __syncthreads();
    if (t < 4) {
        float a = b3[t];
#pragma unroll
        for (int k = 0; k < 32; ++k) a += W3[t * 32 + k] * o2[k];
        out[bidx * 4 + t] = a;
    }
}

// ---------------------------------------------------------------------------
extern "C" void kernel_launch(void* const* d_in, const int* in_sizes, int n_in,
                              void* d_out, int out_size, void* d_ws, size_t ws_size,
                              hipStream_t stream) {
    const float* x   = (const float*)d_in[0];
    const float* Wih = (const float*)d_in[1];
    const float* Whh = (const float*)d_in[2];
    const float* bih = (const float*)d_in[3];
    const float* bhh = (const float*)d_in[4];
    const float* W1  = (const float*)d_in[5];
    const float* b1  = (const float*)d_in[6];
    const float* W2  = (const float*)d_in[7];
    const float* b2  = (const float*)d_in[8];
    const float* W3  = (const float*)d_in[9];
    const float* b3  = (const float*)d_in[10];
    float* out = (float*)d_out;

    const size_t GXB = GXCH * sizeof(unsigned short);          // 33.55 MB
    unsigned short* gx0 = (unsigned short*)d_ws;
    unsigned short* gx1 = (unsigned short*)((char*)d_ws + GXB);
    float* hc = (float*)((char*)d_ws + 2 * GXB);               // 256 KB
    unsigned short* xb   = (unsigned short*)((char*)d_ws + 2 * GXB + 262144);
    unsigned short* wihb = xb + (size_t)XN;
    unsigned short* whhb = wihb + WIHN;

    // L0: fp32 -> bf16 conversion (pure BW)
    conv_kernel<<<dim3(2048), 256, 0, stream>>>(x, Wih, Whh, xb, wihb, whhb);

    // L1..L5: skewed pipeline. Launch k: GEMM(chunk k) + LSTM(chunk k-1).
    for (int k = 0; k <= NCHUNK; ++k) {
        const int run_gemm = (k < NCHUNK);
        const int run_lstm = (k > 0);
        unsigned short* gg = (k & 1) ? gx1 : gx0;        // gemm writes chunk k
        const unsigned short* gl = ((k - 1) & 1) ? gx1 : gx0; // lstm reads k-1
        fused_kernel<<<dim3(NBLK + NGB), 512, 0, stream>>>(
            xb, wihb, whhb, bih, bhh, gl, gg, hc,
            k * TC, (k == 1) ? 1 : 0, run_lstm, run_gemm);
    }

    head_kernel<<<dim3(BATCH), 64, 0, stream>>>(hc, W1, b1, W2, b2, W3, b3, out);
}

// Round 11
// 515.572 us; speedup vs baseline: 2.6886x; 1.0333x over previous
//
#include <hip/hip_runtime.h>
#include <hip/hip_bf16.h>

// LSTM: B=256, T=512, I=256, H=128 (4H=512 gates), then MLP 128->64->32->4.
// ROUND 17 (2nd resubmit; rounds 9-10 were GPU-acquisition timeouts, no data):
//   delete the conv kernel. GEMM converts fp32->bf16 in staging
//   (round-1 packbf path, bit-identical RNE); LSTM Af-init does f2bf from
//   fp32 Whh (round-0 path, bit-identical). Removes a ~33us serialized
//   dispatch + one launch boundary; mixed dispatches absorb +17MB x fetch
//   (hidden, ~1TB/s of 8 used).
//   LSTM role: round-2 structure EXACTLY (1 unit/lane, rsel in-lane extract,
//   single 4-deep MFMA chains, PF=4 gx ring, 1 barrier/step). All phase/
//   group/RB restructures are measured-bad (r11/r12/r13/r15) — never again.
//   Schedule: fused k=0..4 (GEMM chunk k + LSTM chunk k-1), TC=128; head.
//
//   gx gate-plane layout (unchanged):
//     idx(g,t,blk2,wj,L) = (((g*TC+t)*64 + blk2)*512) + wj*64 + L
//     blk2=batch>>2, j=gate&127, wj=j>>4, L=(j&15)*4+(batch&3).

#define TC       128
#define NCHUNK   4
#define BATCH    256
#define TSEQ     512
#define ISZ      256
#define HSZ      128
#define RB       4
#define NBLK     (BATCH / RB)     // 64 lstm blocks
#define NGB      (2 * TC * 4)     // 1024 gemm blocks
#define HROW     144              // shorts; 72 dwords = 8 mod 32 -> 2-way only
#define GX_PER_T 131072           // gx elements per timestep (all 4 planes)
#define GXCH     ((size_t)TC * GX_PER_T)   // shorts per gx buffer (33.55MB)
#define STRT     32768            // per-t stride in shorts (64*512)
#define PF       4                // gx prefetch depth in steps

typedef __attribute__((ext_vector_type(8))) short short8;
typedef __attribute__((ext_vector_type(4))) float f32x4;

__device__ __forceinline__ void barrier_nodrain() {
    // s_barrier WITHOUT the compiler's vmcnt(0) drain: LDS consistency only.
    __asm__ __volatile__("s_waitcnt lgkmcnt(0)\n\ts_barrier" ::: "memory");
}

__device__ __forceinline__ float fast_rcp(float x) {
    return __builtin_amdgcn_rcpf(x);
}
__device__ __forceinline__ float sigmoidf_(float x) {
    return fast_rcp(1.0f + __expf(-x));
}
__device__ __forceinline__ float tanhf_(float x) {
    float e = __expf(2.0f * x);               // inf-safe
    return 1.0f - 2.0f * fast_rcp(e + 1.0f);
}
__device__ __forceinline__ unsigned short f2bf(float x) {  // fp32 -> bf16 RNE
    union { float f; unsigned u; } v; v.f = x;
    unsigned r = v.u + 0x7fffu + ((v.u >> 16) & 1u);
    return (unsigned short)(r >> 16);
}
__device__ __forceinline__ float bf2f(unsigned short b) {
    union { unsigned u; float f; } v;
    v.u = ((unsigned)b) << 16;
    return v.f;
}
__device__ __forceinline__ unsigned packbf(float lo, float hi) {  // packed HW cvt
    __hip_bfloat162 h2 = __float22bfloat162_rn(make_float2(lo, hi));
    union { __hip_bfloat162 h; unsigned u; } v; v.h = h2;
    return v.u;
}
__device__ __forceinline__ float sel4(f32x4 v, int r) {   // v[r], 3 cndmask
    float s01 = (r & 1) ? v[1] : v[0];
    float s23 = (r & 1) ? v[3] : v[2];
    return (r & 2) ? s23 : s01;
}

// ---------------------------------------------------------------------------
// Fused kernel: blocks [0,NBLK) lstm (reads gxl), [NBLK,..) gemm (writes gxg
// for timestep base t0). Either role can be disabled.
__global__ __launch_bounds__(512, 2) void fused_kernel(
    const float* __restrict__ x, const float* __restrict__ Wih,
    const float* __restrict__ Whh,
    const float* __restrict__ bih, const float* __restrict__ bhh,
    const unsigned short* __restrict__ gxl, unsigned short* __restrict__ gxg,
    float* __restrict__ hc, int t0, int first, int run_lstm, int run_gemm)
{
    __shared__ __align__(16) char smem[32768];
    const int tid  = threadIdx.x;
    const int w    = tid >> 6;
    const int lane = tid & 63;
    const int n    = lane & 15;
    const int quad = lane >> 4;

    if (blockIdx.x >= NBLK) {
        // ===================== GEMM role (gx for chunk at t0) ===============
        if (!run_gemm) return;
        short* As = (short*)smem;            // [2][128*32] bf16, 16 KB
        short* Bs = (short*)(smem + 16384);  // [2][128*32] bf16, 16 KB

        const int gb = (int)blockIdx.x - NBLK;
        const int nt = gb & 3;               // gate plane
        const int mt = gb >> 2;
        const int tl = mt >> 1;              // timestep within chunk (0..127)
        const int b0 = (mt & 1) * 128;       // batch half
        const int n0 = nt * 128;

        const int mq = w & 1;                // wave grid 2(m) x 4(n)
        const int nq = w >> 1;

        const int srow = tid >> 2;           // 0..127 staging row
        const int skh  = (tid & 3) * 8;      // elem offset within 32-k slice

        const float* xr = x + ((size_t)(b0 + srow) * TSEQ + (size_t)(t0 + tl)) * ISZ + skh;
        const float* wr = Wih + (size_t)(n0 + srow) * ISZ + skh;

        f32x4 acc[4][2];
#pragma unroll
        for (int mi = 0; mi < 4; ++mi)
#pragma unroll
            for (int ni = 0; ni < 2; ++ni)
                acc[mi][ni] = (f32x4){0.f, 0.f, 0.f, 0.f};

        {   // stage k-slice 0 (fp32 -> bf16 in staging, RNE identical)
            float4 a0 = *(const float4*)(xr);
            float4 a1 = *(const float4*)(xr + 4);
            float4 b0v = *(const float4*)(wr);
            float4 b1v = *(const float4*)(wr + 4);
            *(uint4*)(&As[srow * 32 + skh]) =
                (uint4){packbf(a0.x, a0.y), packbf(a0.z, a0.w),
                        packbf(a1.x, a1.y), packbf(a1.z, a1.w)};
            *(uint4*)(&Bs[srow * 32 + skh]) =
                (uint4){packbf(b0v.x, b0v.y), packbf(b0v.z, b0v.w),
                        packbf(b1v.x, b1v.y), packbf(b1v.z, b1v.w)};
        }
        barrier_nodrain();

        for (int ks = 0; ks < 8; ++ks) {
            const int cur = (ks & 1) * 4096;
            const int nxt = 4096 - cur;
            float4 a0, a1, b0v, b1v;
            if (ks < 7) {
                a0  = *(const float4*)(xr + (ks + 1) * 32);
                a1  = *(const float4*)(xr + (ks + 1) * 32 + 4);
                b0v = *(const float4*)(wr + (ks + 1) * 32);
                b1v = *(const float4*)(wr + (ks + 1) * 32 + 4);
            }
            short8 af[4], bfr[2];
#pragma unroll
            for (int mi = 0; mi < 4; ++mi)
                af[mi] = *(const short8*)(&As[cur + (mq * 64 + mi * 16 + n) * 32 + quad * 8]);
#pragma unroll
            for (int ni = 0; ni < 2; ++ni)
                bfr[ni] = *(const short8*)(&Bs[cur + (nq * 32 + ni * 16 + n) * 32 + quad * 8]);
#pragma unroll
            for (int mi = 0; mi < 4; ++mi)
#pragma unroll
                for (int ni = 0; ni < 2; ++ni)
                    acc[mi][ni] = __builtin_amdgcn_mfma_f32_16x16x32_bf16(
                        af[mi], bfr[ni], acc[mi][ni], 0, 0, 0);
            if (ks < 7) {
                *(uint4*)(&As[nxt + srow * 32 + skh]) =
                    (uint4){packbf(a0.x, a0.y), packbf(a0.z, a0.w),
                            packbf(a1.x, a1.y), packbf(a1.z, a1.w)};
                *(uint4*)(&Bs[nxt + srow * 32 + skh]) =
                    (uint4){packbf(b0v.x, b0v.y), packbf(b0v.z, b0v.w),
                            packbf(b1v.x, b1v.y), packbf(b1v.z, b1v.w)};
            }
            barrier_nodrain();
        }

        // epilogue: bias + bf16, gate-plane layout, 8-B contiguous stores.
#pragma unroll
        for (int ni = 0; ni < 2; ++ni) {
            const int j    = nq * 32 + ni * 16 + n;
            const int gate = n0 + j;
            const float bias = bih[gate] + bhh[gate];
            const int wj = nq * 2 + ni;                       // j >> 4
#pragma unroll
            for (int mi = 0; mi < 4; ++mi) {
                const int bb   = b0 + mq * 64 + mi * 16 + quad * 4;
                const int blk2 = bb >> 2;
                const size_t idx = ((((size_t)nt * TC + tl) * 64 + blk2) * 512) +
                                   (size_t)wj * 64 + (size_t)n * 4;
                const unsigned lo = packbf(acc[mi][ni][0] + bias, acc[mi][ni][1] + bias);
                const unsigned hi = packbf(acc[mi][ni][2] + bias, acc[mi][ni][3] + bias);
                *(uint2*)(&gxg[idx]) = (uint2){lo, hi};
            }
        }
        return;
    }

    // ======================= LSTM role (round-2 structure) ==================
    if (!run_lstm) return;
    __builtin_amdgcn_s_setprio(1);   // latency-critical chain wins issue arb
    short* h_lds = (short*)smem;     // [2*RB*HROW] bf16 double-buffered h

    const int blk  = (int)blockIdx.x;
    const int b0   = blk * RB;
    const int nb   = lane & 3;           // unit batch
    const int jl   = lane >> 2;          // unit j-local 0..15
    const int j    = 16 * w + jl;        // unit hidden index
    const int rsel = jl & 3;             // D-reg holding this unit's gate

    // static A-frags: f2bf from fp32 Whh (bit-identical to pre-converted)
    short8 Af[4][4];
#pragma unroll
    for (int g = 0; g < 4; ++g) {
        const float* row = Whh + (size_t)(128 * g + 16 * w + n) * HSZ + 8 * quad;
#pragma unroll
        for (int ks = 0; ks < 4; ++ks)
#pragma unroll
            for (int i = 0; i < 8; ++i)
                Af[g][ks][i] = (short)f2bf(row[32 * ks + i]);
    }

    // init unit state: every thread owns one (j, b) unit
    float c1 = 0.f, hl1 = 0.f;
    {
        unsigned short h0 = 0;
        if (!first) {
            c1 = hc[(size_t)BATCH * HSZ + (size_t)(b0 + nb) * HSZ + j];
            h0 = f2bf(hc[(size_t)(b0 + nb) * HSZ + j]);
        }
        *(unsigned short*)&h_lds[nb * HROW + j] = h0;   // buffer 0
    }

    // gx: 4 coalesced ushort loads per lane per step (one per gate plane)
    const unsigned short* gp[4];
#pragma unroll
    for (int g = 0; g < 4; ++g)
        gp[g] = gxl + (((size_t)g * TC) * 64 + blk) * 512 + (size_t)w * 64 + lane;

    unsigned short gq[PF][4];
#pragma unroll
    for (int d = 0; d < PF; ++d)
#pragma unroll
        for (int g = 0; g < 4; ++g)
            gq[d][g] = gp[g][(size_t)d * STRT];

    barrier_nodrain();

    for (int t = 0; t < TC; t += PF) {
#pragma unroll
        for (int u = 0; u < PF; ++u) {
            const int tt = t + u;
            const short* hb_r = h_lds + (u & 1) * (RB * HROW);
            short*       hb_w = h_lds + ((u & 1) ^ 1) * (RB * HROW);

            short8 Bf[4];
#pragma unroll
            for (int ks = 0; ks < 4; ++ks)
                Bf[ks] = *(const short8*)(&hb_r[nb * HROW + 32 * ks + 8 * quad]);

            // MFMAs: zero-C first, 4 independent 4-deep chains (one per gate)
            f32x4 acc[4];
#pragma unroll
            for (int g = 0; g < 4; ++g)
                acc[g] = __builtin_amdgcn_mfma_f32_16x16x32_bf16(
                    Af[g][0], Bf[0], (f32x4){0.f, 0.f, 0.f, 0.f}, 0, 0, 0);
#pragma unroll
            for (int ks = 1; ks < 4; ++ks)
#pragma unroll
                for (int g = 0; g < 4; ++g)
                    acc[g] = __builtin_amdgcn_mfma_f32_16x16x32_bf16(
                        Af[g][ks], Bf[ks], acc[g], 0, 0, 0);

            // in-lane gate extract: unit (jl,nb)'s value is THIS lane's
            // acc[g][rsel] (D row = 4*quad+reg = jl, D col batch = nb).
            const float s0 = sel4(acc[0], rsel) + bf2f(gq[u][0]);
            const float s1 = sel4(acc[1], rsel) + bf2f(gq[u][1]);
            const float s2 = sel4(acc[2], rsel) + bf2f(gq[u][2]);
            const float s3 = sel4(acc[3], rsel) + bf2f(gq[u][3]);

            // reload ring slot u (just consumed) for step tt+PF; vmcnt wait
            // for these loads lands PF steps from now.
            const int tf = (tt + PF < TC) ? (tt + PF) : (TC - 1);
#pragma unroll
            for (int g = 0; g < 4; ++g)
                gq[u][g] = gp[g][(size_t)tf * STRT];

            const float ig = sigmoidf_(s0);
            const float fg = sigmoidf_(s1);
            const float gg = tanhf_(s2);
            const float og = sigmoidf_(s3);
            c1  = fg * c1 + ig * gg;
            hl1 = og * tanhf_(c1);

            *(unsigned short*)&hb_w[nb * HROW + j] = f2bf(hl1);
            barrier_nodrain();
        }
    }

    hc[(size_t)(b0 + nb) * HSZ + j] = hl1;
    hc[(size_t)BATCH * HSZ + (size_t)(b0 + nb) * HSZ + j] = c1;
}

// ---------------------------------------------------------------------------
// MLP head: one block (64 threads) per batch row.
__global__ __launch_bounds__(64) void head_kernel(
    const float* __restrict__ hc,
    const float* __restrict__ W1, const float* __restrict__ b1,
    const float* __restrict__ W2, const float* __restrict__ b2,
    const float* __restrict__ W3, const float* __restrict__ b3,
    float* __restrict__ out)
{
    __shared__ float hs[HSZ];
    __shared__ float o1[64];
    __shared__ float o2[32];
    const int bidx = blockIdx.x;
    const int t = threadIdx.x;
    hs[t]      = hc[bidx * HSZ + t];
    hs[t + 64] = hc[bidx * HSZ + t + 64];
    __syncthreads();
    {
        float a = b1[t];
#pragma unroll 8
        for (int k = 0; k < HSZ; ++k) a += W1[t * HSZ + k] * hs[k];
        o1[t] = fmaxf(a, 0.0f);
    }
    __syncthreads();
    if (t < 32) {
        float a = b2[t];
#pragma unroll 8
        for (int k = 0; k < 64; ++k) a += W2[t * 64 + k] * o1[k];
        o2[t] = fmaxf(a, 0.0f);
    }
    __syncthreads();
    if (t < 4) {
        float a = b3[t];
#pragma unroll
        for (int k = 0; k < 32; ++k) a += W3[t * 32 + k] * o2[k];
        out[bidx * 4 + t] = a;
    }
}

// ---------------------------------------------------------------------------
extern "C" void kernel_launch(void* const* d_in, const int* in_sizes, int n_in,
                              void* d_out, int out_size, void* d_ws, size_t ws_size,
                              hipStream_t stream) {
    const float* x   = (const float*)d_in[0];
    const float* Wih = (const float*)d_in[1];
    const float* Whh = (const float*)d_in[2];
    const float* bih = (const float*)d_in[3];
    const float* bhh = (const float*)d_in[4];
    const float* W1  = (const float*)d_in[5];
    const float* b1  = (const float*)d_in[6];
    const float* W2  = (const float*)d_in[7];
    const float* b2  = (const float*)d_in[8];
    const float* W3  = (const float*)d_in[9];
    const float* b3  = (const float*)d_in[10];
    float* out = (float*)d_out;

    const size_t GXB = GXCH * sizeof(unsigned short);          // 33.55 MB
    unsigned short* gx0 = (unsigned short*)d_ws;
    unsigned short* gx1 = (unsigned short*)((char*)d_ws + GXB);
    float* hc = (float*)((char*)d_ws + 2 * GXB);               // 256 KB

    // Skewed pipeline, no conv: launch k = GEMM(chunk k) + LSTM(chunk k-1).
    for (int k = 0; k <= NCHUNK; ++k) {
        const int run_gemm = (k < NCHUNK);
        const int run_lstm = (k > 0);
        unsigned short* gg = (k & 1) ? gx1 : gx0;        // gemm writes chunk k
        const unsigned short* gl = ((k - 1) & 1) ? gx1 : gx0; // lstm reads k-1
        fused_kernel<<<dim3(NBLK + NGB), 512, 0, stream>>>(
            x, Wih, Whh, bih, bhh, gl, gg, hc,
            k * TC, (k == 1) ? 1 : 0, run_lstm, run_gemm);
    }

    head_kernel<<<dim3(BATCH), 64, 0, stream>>>(hc, W1, b1, W2, b2, W3, b3, out);
}